// Round 3
// baseline (364.919 us; speedup 1.0000x reference)
//
#include <hip/hip_runtime.h>
#include <hip/hip_bf16.h>
#include <hip/hip_fp16.h>

#define E4M3_MAX 240.0f

typedef __attribute__((ext_vector_type(8))) __bf16 bf16x8;
typedef __attribute__((ext_vector_type(4))) float f32x4;
typedef unsigned short ushort_t;

__device__ __forceinline__ void gload_lds16(const void* g, void* l) {
  __builtin_amdgcn_global_load_lds(
      (const __attribute__((address_space(1))) void*)g,
      (__attribute__((address_space(3))) void*)l,
      16, 0, 0);
}

// ---------------- amax over |weight| ----------------
__global__ void amax_abs_kernel(const float* __restrict__ w, int n4,
                                unsigned* __restrict__ amax_bits) {
  float m = 0.0f;
  const float4* w4 = (const float4*)w;
  int stride = gridDim.x * blockDim.x;
  for (int i = blockIdx.x * blockDim.x + threadIdx.x; i < n4; i += stride) {
    float4 v = w4[i];
    m = fmaxf(m, fmaxf(fmaxf(fabsf(v.x), fabsf(v.y)),
                       fmaxf(fabsf(v.z), fabsf(v.w))));
  }
  for (int off = 32; off > 0; off >>= 1)
    m = fmaxf(m, __shfl_down(m, off, 64));
  __shared__ float smax[4];
  int l = threadIdx.x & 63, wv = threadIdx.x >> 6;
  if (l == 0) smax[wv] = m;
  __syncthreads();
  if (threadIdx.x == 0) {
    float bm = fmaxf(fmaxf(smax[0], smax[1]), fmaxf(smax[2], smax[3]));
    atomicMax(amax_bits, __float_as_uint(bm));
  }
}

// ---------------- quantize weight -> bf16 qw ----------------
__global__ void quant_weight_kernel(const float* __restrict__ w,
                                    const unsigned* __restrict__ amax_bits,
                                    ushort_t* __restrict__ qw, int n4) {
  float amax = __uint_as_float(*amax_bits);
  float scale = fmaxf(amax / E4M3_MAX, 1e-10f);
  const float4* w4 = (const float4*)w;
  ushort4* q4 = (ushort4*)qw;
  int stride = gridDim.x * blockDim.x;
  for (int i = blockIdx.x * blockDim.x + threadIdx.x; i < n4; i += stride) {
    float4 v = w4[i];
    float r[4] = {v.x, v.y, v.z, v.w};
    ushort_t o[4];
#pragma unroll
    for (int j = 0; j < 4; ++j) {
      float s = fminf(fmaxf(r[j] / scale, -E4M3_MAX), E4M3_MAX);
      s = __half2float(__float2half(s));   // fp16 round-trip (RNE)
      float q = rintf(s * 8.0f) * 0.125f;  // mantissa grid, half-to-even
      q = fminf(fmaxf(q, -E4M3_MAX), E4M3_MAX);
      __hip_bfloat16 h = __float2bfloat16(q * scale);
      o[j] = *(ushort_t*)&h;
    }
    ushort4 ov = {o[0], o[1], o[2], o[3]};
    q4[i] = ov;
  }
}

// ---------------- convert x fp32 -> bf16 ----------------
__global__ void cvt_bf16_kernel(const float* __restrict__ x,
                                ushort_t* __restrict__ xb, int n4) {
  const float4* x4 = (const float4*)x;
  ushort4* o4 = (ushort4*)xb;
  int stride = gridDim.x * blockDim.x;
  for (int i = blockIdx.x * blockDim.x + threadIdx.x; i < n4; i += stride) {
    float4 v = x4[i];
    __hip_bfloat16 h0 = __float2bfloat16(v.x);
    __hip_bfloat16 h1 = __float2bfloat16(v.y);
    __hip_bfloat16 h2 = __float2bfloat16(v.z);
    __hip_bfloat16 h3 = __float2bfloat16(v.w);
    ushort4 o = {*(ushort_t*)&h0, *(ushort_t*)&h1,
                 *(ushort_t*)&h2, *(ushort_t*)&h3};
    o4[i] = o;
  }
}

// ============ 256x256 pipelined 4-phase/K-tile bf16 GEMM ============
// C = A * Bt^T + bias.  A: [8192][4096] bf16, Bt: [4096][4096] bf16, C fp32.
// 8 waves (2M x 4N), BK=64, dbuf LDS 128 KiB.  ds_reads issued one phase
// ahead of their MFMA (reg-double-buffered frags), counted lgkm waits,
// ONE barrier per phase, single vmcnt(0)/tile at the natural empty point.

#define BAR() do { asm volatile("" ::: "memory"); \
                   __builtin_amdgcn_s_barrier(); \
                   asm volatile("" ::: "memory"); } while (0)
#define LGKM(n) do { asm volatile("s_waitcnt lgkmcnt(" #n ")" ::: "memory"); \
                     __builtin_amdgcn_sched_barrier(0); } while (0)
#define VMC(n)  do { asm volatile("s_waitcnt vmcnt(" #n ")" ::: "memory"); \
                     __builtin_amdgcn_sched_barrier(0); } while (0)

__global__ __launch_bounds__(512, 2) void gemm256_pipe(
    const ushort_t* __restrict__ A, const ushort_t* __restrict__ Bt,
    const float* __restrict__ bias, float* __restrict__ C) {
  constexpr int K = 4096, N = 4096;
  __shared__ __align__(16) ushort_t As[2][2][8192];
  __shared__ __align__(16) ushort_t Bs[2][2][8192];

  const int tid = threadIdx.x;
  const int wid = tid >> 6, lane = tid & 63;
  const int wm = wid >> 2, wn = wid & 3;     // 2 x 4 wave grid
  const int lk = lane >> 4, lr = lane & 15;

  // XCD swizzle (nwg = 512, divisible by 8)
  int bid = blockIdx.x;
  int swz = (bid & 7) * 64 + (bid >> 3);
  int bm = swz >> 4, bn = swz & 15;          // nbn = 16

  const ushort_t* Ab = A + (size_t)bm * 256 * K;
  const ushort_t* Bb = Bt + (size_t)bn * 256 * K;

  // staging: slot s = q*512+tid; row = s>>3; granule c = (s&7)^(row&7)
  int offG[2];
#pragma unroll
  for (int q = 0; q < 2; ++q) {
    int s = q * 512 + tid;
    int row = s >> 3;
    int c = (s & 7) ^ (row & 7);
    offG[q] = row * K + c * 8;
  }

  // stage BOTH halves of one matrix tile (4 loads/thread)
#define STAGE_A2(buf, kt)                                                  \
  do { _Pragma("unroll") for (int h = 0; h < 2; ++h)                       \
    _Pragma("unroll") for (int q = 0; q < 2; ++q)                          \
      gload_lds16(Ab + (size_t)h * 128 * K + (kt) * 64 + offG[q],          \
                  &As[buf][h][(q * 512 + wid * 64) * 8]); } while (0)
#define STAGE_B2(buf, kt)                                                  \
  do { _Pragma("unroll") for (int h = 0; h < 2; ++h)                       \
    _Pragma("unroll") for (int q = 0; q < 2; ++q)                          \
      gload_lds16(Bb + (size_t)h * 128 * K + (kt) * 64 + offG[q],          \
                  &Bs[buf][h][(q * 512 + wid * 64) * 8]); } while (0)

  // swizzled ds_read addressing
  const int abase = lr * 64;
  const int bbase = (wn & 1) * 4096 + lr * 64;
  const int bhalf = wn >> 1;
  const int xk0 = ((lk) ^ (lr & 7)) * 8;
  const int xk1 = ((4 + lk) ^ (lr & 7)) * 8;

  bf16x8 afX[4], afY[4], bfE[4], bfO[4];
  f32x4 acc[8][4] = {};

#define RD_A(dst, buf, fi0, xkv)                                           \
  do { _Pragma("unroll") for (int i = 0; i < 4; ++i)                       \
    dst[i] = *(const bf16x8*)&As[buf][wm][abase + ((fi0) + i) * 1024 + (xkv)]; } while (0)
#define RD_B4(dst, buf, xkv)                                               \
  do { _Pragma("unroll") for (int j = 0; j < 4; ++j)                       \
    dst[j] = *(const bf16x8*)&Bs[buf][bhalf][bbase + j * 1024 + (xkv)]; } while (0)
#define RD_B2(dst, j0, buf, xkv)                                           \
  do { _Pragma("unroll") for (int j = 0; j < 2; ++j)                       \
    dst[(j0) + j] = *(const bf16x8*)&Bs[buf][bhalf][bbase + ((j0) + j) * 1024 + (xkv)]; } while (0)

#define MMA(areg, breg, H)                                                 \
  do { __builtin_amdgcn_s_setprio(1);                                      \
    _Pragma("unroll") for (int i = 0; i < 4; ++i)                          \
      _Pragma("unroll") for (int j = 0; j < 4; ++j)                        \
        acc[(H) * 4 + i][j] = __builtin_amdgcn_mfma_f32_16x16x32_bf16(     \
            areg[i], breg[j], acc[(H) * 4 + i][j], 0, 0, 0);               \
    __builtin_amdgcn_s_setprio(0);                                         \
    __builtin_amdgcn_sched_barrier(0); } while (0)

  // one K-tile = 4 phases; reads in phase p feed phase p+1's MFMA.
  //  Q1: rd afY<-A[4:8]k0, bfO[0:2]<-B k1 (6); stage A(t+1);  lgkm(6); MMA(afX,bfE,0)
  //  Q2: rd afX<-A[0:4]k1, bfO[2:4]      (6);                 lgkm(6); MMA(afY,bfE,1)
  //  Q3: rd afY<-A[4:8]k1                (4);                 lgkm(4); MMA(afX,bfO,0); VMC(0)
  //  Q4: rd afX<-A'[0:4]k0, bfE<-B' k0   (8); stage B(t+2);   lgkm(8); MMA(afY,bfO,1)
#define TILE(buf, obuf, t, DO_SA, DO_SB, LAST)                             \
  do {                                                                     \
    RD_A(afY, buf, 4, xk0); RD_B2(bfO, 0, buf, xk1);                       \
    if (DO_SA) STAGE_A2(obuf, (t) + 1);                                    \
    LGKM(6); MMA(afX, bfE, 0); BAR();                                      \
    RD_A(afX, buf, 0, xk1); RD_B2(bfO, 2, buf, xk1);                       \
    LGKM(6); MMA(afY, bfE, 1); BAR();                                      \
    RD_A(afY, buf, 4, xk1);                                                \
    LGKM(4); MMA(afX, bfO, 0); VMC(0); BAR();                              \
    if (!(LAST)) { RD_A(afX, obuf, 0, xk0); RD_B4(bfE, obuf, xk0); }       \
    if (DO_SB) STAGE_B2(buf, (t) + 2);                                     \
    if (!(LAST)) { LGKM(8); MMA(afY, bfO, 1); BAR(); }                     \
    else         { LGKM(0); MMA(afY, bfO, 1); }                            \
  } while (0)

  // ---- prologue ----
  STAGE_A2(0, 0); STAGE_B2(0, 0);   // tile 0 (8 loads)
  STAGE_B2(1, 1);                   // B of tile 1 (4 loads)
  VMC(4);                           // retire tile 0; B(1) stays in flight
  BAR();
  RD_A(afX, 0, 0, xk0); RD_B4(bfE, 0, xk0);   // frags for Q1(0)

  // ---- main loop: tiles 0..61 ----
  for (int t = 0; t < 62; t += 2) {
    TILE(0, 1, t, 1, 1, 0);         // even tile: stage A(t+1)->buf1, B(t+2)->buf0
    TILE(1, 0, t + 1, 1, 1, 0);     // odd tile:  stage A(t+2)->buf0, B(t+3)->buf1
  }
  // ---- tiles 62, 63 ----
  TILE(0, 1, 62, 1, 0, 0);          // stage A(63); no B(64)
  TILE(1, 0, 63, 0, 0, 1);          // no stages, no next reads

  // ---- C write + bias (D: col = lane&15 -> n, row = lk*4+reg -> m) ----
  float* Cb = C + (size_t)(bm * 256 + wm * 128) * N + bn * 256 + wn * 64;
#pragma unroll
  for (int fj = 0; fj < 4; ++fj) {
    int n = fj * 16 + lr;
    float bv = bias[bn * 256 + wn * 64 + n];
#pragma unroll
    for (int fi = 0; fi < 8; ++fi) {
      int m0 = fi * 16 + lk * 4;
#pragma unroll
      for (int r = 0; r < 4; ++r)
        Cb[(size_t)(m0 + r) * N + n] = acc[fi][fj][r] + bv;
    }
  }
}

extern "C" void kernel_launch(void* const* d_in, const int* in_sizes, int n_in,
                              void* d_out, int out_size, void* d_ws, size_t ws_size,
                              hipStream_t stream) {
  const float* x = (const float*)d_in[0];     // [4,2048,4096] fp32
  const float* wt = (const float*)d_in[1];    // [4096,4096] fp32
  const float* bias = (const float*)d_in[2];  // [4096] fp32
  float* out = (float*)d_out;                 // [4,2048,4096] fp32

  const int DIN = 4096;
  const int NW = in_sizes[1];                 // 16777216
  const int M = in_sizes[0] / DIN;            // 8192

  char* ws = (char*)d_ws;
  unsigned* amax_bits = (unsigned*)ws;
  ushort_t* qw = (ushort_t*)(ws + 256);                    // bf16 [4096][4096]
  ushort_t* xb = (ushort_t*)(ws + 256 + (size_t)NW * 2);   // bf16 [8192][4096]

  hipMemsetAsync(amax_bits, 0, 4, stream);
  hipLaunchKernelGGL(amax_abs_kernel, dim3(1024), dim3(256), 0, stream,
                     wt, NW / 4, amax_bits);
  hipLaunchKernelGGL(quant_weight_kernel, dim3(2048), dim3(256), 0, stream,
                     wt, amax_bits, qw, NW / 4);
  hipLaunchKernelGGL(cvt_bf16_kernel, dim3(2048), dim3(256), 0, stream,
                     x, xb, (M * DIN) / 4);

  hipLaunchKernelGGL(gemm256_pipe, dim3(512), dim3(512), 0, stream,
                     xb, qw, bias, out);
}